// Round 2
// baseline (356.099 us; speedup 1.0000x reference)
//
#include <hip/hip_runtime.h>

#define NB 256
#define NT 4096
#define CH 128
#define NCHUNK (NT / CH)

typedef unsigned int u32;
typedef unsigned long long u64;

typedef __attribute__((address_space(1))) const u32 gas_u32;
typedef __attribute__((address_space(3))) u32 las_u32;

__device__ __forceinline__ void gll16(const void* g, void* l) {
  __builtin_amdgcn_global_load_lds((gas_u32*)g, (las_u32*)l, 16, 0, 0);
}

template <int CTRL>
__device__ __forceinline__ float dppf(float x) {
  return __int_as_float(__builtin_amdgcn_update_dpp(
      0, __float_as_int(x), CTRL, 0xF, 0xF, true));
}

__global__ void __launch_bounds__(64, 1)
viterbi_k(const float* __restrict__ feats, const float* __restrict__ trans,
          float* __restrict__ out) {
  // LDS: 36864 + 6144 + 16384 + 4096 = 63488 B (< 64KB)
  __shared__ __align__(16) float s_tr[2 * CH * 36];
  __shared__ __align__(16) float s_ft[2 * CH * 6];
  __shared__ u32 s_psi[NT];
  __shared__ u32 s_path[NT / 4];

  const int b = blockIdx.x;
  const int lane = (int)threadIdx.x;
  const int g = lane >> 3;        // output state i (0..7; 6,7 idle)
  const int l = lane & 7;         // predecessor j (0..7; 6,7 idle)
  const bool lhi = (l >= 6);
  const bool sel4 = (lane & 4) != 0;
  const int gg = (g < 6) ? g : 5;
  const int jj = lhi ? 5 : l;
  const int troff = gg * 6 + jj;              // word offset inside a 36-word row
  const int ftoff = gg;                       // word offset inside a 6-word row
  const int bp_addr = ((l * 8 + g) << 2);     // transpose source lane * 4
  const float ninf = __int_as_float(0xff800000u);

  const float* trb = trans + (size_t)b * NT * 36;
  const float* ftb = feats + (size_t)b * NT * 6;

  // lane (g,l) holds delta[l]
  float delta = (l == 4) ? 0.0f : ((l < 6) ? -10000.0f : ninf);
  u32 mlo = 0, mhi = 0;

  auto stage = [&](int c) {
    const int buf = c & 1;
    const float* gt = trb + (size_t)c * CH * 36;
    float* lt = s_tr + buf * (CH * 36);
#pragma unroll
    for (int i = 0; i < 18; ++i) gll16(gt + i * 256 + lane * 4, lt + i * 256);
    const float* gf = ftb + (size_t)c * CH * 6;
    float* lf = s_ft + buf * (CH * 6);
#pragma unroll
    for (int i = 0; i < 3; ++i) gll16(gf + i * 256 + lane * 4, lf + i * 256);
  };

  // tr is pre-masked to -inf at idle j-lanes (off the dependence chain).
  auto step = [&](float tr, float ft, int slot) {
    float s = tr + delta;            // exact: same single add as reference
    float m = fmaxf(s, dppf<0xB1>(s));                 // xor1 (quad_perm 1,0,3,2)
    m = fmaxf(m, dppf<0x4E>(m));                       // xor2 (quad_perm 2,3,0,1)
    float r4 = dppf<0x124>(m);                         // row_ror:4  (from lane i-4)
    float r12 = dppf<0x12C>(m);                        // row_ror:12 (from lane i+4)
    m = fmaxf(m, sel4 ? r4 : r12);                     // xor4 within 8-group (FIXED)
    u64 bal = __ballot(s == m);                        // psi witnesses, bit = 8i+j
    bool cap = (lane == slot);
    mlo = cap ? (u32)bal : mlo;
    mhi = cap ? (u32)(bal >> 32) : mhi;
    // delta_new[g] at all lanes of group g; transpose so lane (g,l) gets delta_new[l]
    delta = __int_as_float(
        __builtin_amdgcn_ds_bpermute(bp_addr, __float_as_int(m + ft)));
  };

  auto flush = [&](int base) {  // base = multiple of 64; lane holds step base+lane's mask
    const u32 ub = (u32)(base >> 6) & 63;
    u32 p = (u32)__builtin_ctz((mlo & 63u) | 64u);
    p |= (u32)__builtin_ctz(((mlo >> 8) & 63u) | 64u) << 3;
    p |= (u32)__builtin_ctz(((mlo >> 16) & 63u) | 64u) << 6;
    p |= (u32)__builtin_ctz(((mlo >> 24) & 63u) | 64u) << 9;
    p |= (u32)__builtin_ctz((mhi & 63u) | 64u) << 12;
    p |= (u32)__builtin_ctz(((mhi >> 8) & 63u) | 64u) << 15;
    s_psi[base + (((u32)lane) ^ ub)] = p;   // bank-swizzled slot
  };

  stage(0);
  asm volatile("s_waitcnt vmcnt(0)" ::: "memory");
  stage(1);

  // ---- chunk 0 (t = 1..127; t=0 is skipped: init delta has no feat/trans)
  {
    const float* trp = s_tr + troff;
    const float* ftp = s_ft + ftoff;
#pragma unroll
    for (int k = 1; k < 8; ++k) {
      float tv = lhi ? ninf : trp[k * 36];
      step(tv, ftp[k * 6], k);
    }
    for (int k8 = 8; k8 < CH; k8 += 8) {
      float trv[8], ftv[8];
#pragma unroll
      for (int q = 0; q < 8; ++q) {
        trv[q] = lhi ? ninf : trp[(k8 + q) * 36];
        ftv[q] = ftp[(k8 + q) * 6];
      }
#pragma unroll
      for (int q = 0; q < 8; ++q) step(trv[q], ftv[q], (k8 + q) & 63);
      if ((k8 & 63) == 56) flush(k8 - 56);
    }
  }

  // ---- chunks 1..31
  for (int c = 1; c < NCHUNK; ++c) {
    asm volatile("s_waitcnt vmcnt(0)" ::: "memory");   // chunk c resident
    if (c + 1 < NCHUNK) stage(c + 1);
    const int buf = c & 1;
    const float* trp = s_tr + buf * (CH * 36) + troff;
    const float* ftp = s_ft + buf * (CH * 6) + ftoff;
    const int tbase = c * CH;
    for (int k8 = 0; k8 < CH; k8 += 8) {
      float trv[8], ftv[8];
#pragma unroll
      for (int q = 0; q < 8; ++q) {
        trv[q] = lhi ? ninf : trp[(k8 + q) * 36];
        ftv[q] = ftp[(k8 + q) * 6];
      }
#pragma unroll
      for (int q = 0; q < 8; ++q) step(trv[q], ftv[q], (k8 + q) & 63);
      if ((k8 & 63) == 56) flush(tbase + k8 - 56);
    }
  }

  // ---- score + last_tag (exact max over final delta)
  float df = lhi ? ninf : delta;
  float sm = fmaxf(df, dppf<0xB1>(df));
  sm = fmaxf(sm, dppf<0x4E>(sm));
  {
    float q4 = dppf<0x124>(sm), q12 = dppf<0x12C>(sm);
    sm = fmaxf(sm, sel4 ? q4 : q12);                   // FIXED (same swap)
  }
  u64 bs = __ballot(df == sm);
  int last_tag = (int)(__builtin_ctzll(bs) & 7);   // first-index tie-break

  __syncthreads();  // all psi visible

  // ---- per-segment backpointer-map composition (exact integer scan)
  const int u = lane;
  u32 Gm = 0u | (1u << 3) | (2u << 6) | (3u << 9) | (4u << 12) | (5u << 15);
  for (int k = 0; k < 64; ++k) {
    u32 p = s_psi[u * 64 + (k ^ u)];
    u32 ng = 0;
#pragma unroll
    for (int x = 0; x < 6; ++x) {
      u32 j = (p >> (3 * x)) & 7;
      u32 v = (Gm >> (3 * j)) & 7;
      ng |= v << (3 * x);
    }
    Gm = ng;
  }

  // ---- boundary-tag chain via readlane (uniform, register-only)
  int bcur = last_tag;
  int my_b = last_tag;  // lane 63
  for (int v = 63; v >= 1; --v) {
    u32 Gv = (u32)__builtin_amdgcn_readlane((int)Gm, v);
    bcur = (int)((Gv >> (3 * bcur)) & 7);
    my_b = (u == v - 1) ? bcur : my_b;
  }

  // ---- per-segment walk, emit path bytes
  {
    int tag = my_b;
    unsigned char* pb = (unsigned char*)s_path;
    pb[u * 64 + 63] = (unsigned char)tag;
    for (int k = 63; k >= 1; --k) {
      u32 p = s_psi[u * 64 + (k ^ u)];
      tag = (int)((p >> (3 * tag)) & 7);
      pb[u * 64 + k - 1] = (unsigned char)tag;
    }
  }
  if (lane == 0) out[b] = sm;
  __syncthreads();

  // ---- coalesced float path store
  float* outp = out + NB + (size_t)b * NT;
#pragma unroll
  for (int i = 0; i < (NT / 4) / 64; ++i) {
    u32 w = s_path[lane + i * 64];
    float4 f;
    f.x = (float)(w & 255u);
    f.y = (float)((w >> 8) & 255u);
    f.z = (float)((w >> 16) & 255u);
    f.w = (float)((w >> 24) & 255u);
    ((float4*)outp)[lane + i * 64] = f;
  }
}

extern "C" void kernel_launch(void* const* d_in, const int* in_sizes, int n_in,
                              void* d_out, int out_size, void* d_ws, size_t ws_size,
                              hipStream_t stream) {
  (void)in_sizes; (void)n_in; (void)out_size; (void)d_ws; (void)ws_size;
  const float* feats = (const float*)d_in[0];
  const float* trans = (const float*)d_in[1];
  float* out = (float*)d_out;
  hipLaunchKernelGGL(viterbi_k, dim3(NB), dim3(64), 0, stream, feats, trans, out);
}

// Round 3
// 311.928 us; speedup vs baseline: 1.1416x; 1.1416x over previous
//
#include <hip/hip_runtime.h>

#define NB 256
#define NT 4096
#define CH 128
#define NCHUNK (NT / CH)

typedef unsigned int u32;
typedef unsigned long long u64;
typedef int v2i __attribute__((ext_vector_type(2)));

typedef __attribute__((address_space(1))) const u32 gas_u32;
typedef __attribute__((address_space(3))) u32 las_u32;

__device__ __forceinline__ void gll16(const void* g, void* l) {
  __builtin_amdgcn_global_load_lds((gas_u32*)g, (las_u32*)l, 16, 0, 0);
}

template <int CTRL>
__device__ __forceinline__ float dppf(float x) {
  return __int_as_float(__builtin_amdgcn_update_dpp(
      0, __float_as_int(x), CTRL, 0xF, 0xF, true));
}

// max with lane^16 partner (cross-row), VALU-speed on gfx950
__device__ __forceinline__ float pl16max(float x) {
#if __has_builtin(__builtin_amdgcn_permlane16_swap)
  v2i r = __builtin_amdgcn_permlane16_swap(__float_as_int(x), __float_as_int(x),
                                           false, false);
  return fmaxf(__int_as_float(r[0]), __int_as_float(r[1]));
#else
  return fmaxf(x, __shfl_xor(x, 16, 64));
#endif
}

// max with lane^32 partner
__device__ __forceinline__ float pl32max(float x) {
#if __has_builtin(__builtin_amdgcn_permlane32_swap)
  v2i r = __builtin_amdgcn_permlane32_swap(__float_as_int(x), __float_as_int(x),
                                           false, false);
  return fmaxf(__int_as_float(r[0]), __int_as_float(r[1]));
#else
  return fmaxf(x, __shfl_xor(x, 32, 64));
#endif
}

__global__ void __launch_bounds__(64, 1)
viterbi_k(const float* __restrict__ feats, const float* __restrict__ trans,
          float* __restrict__ out) {
  // LDS: 36864 + 6144 + 16384 + 4096 = 63488 B (< 64KB)
  __shared__ __align__(16) float s_tr[2 * CH * 36];
  __shared__ __align__(16) float s_ft[2 * CH * 6];
  __shared__ u32 s_psi[NT];
  __shared__ u32 s_path[NT / 4];

  const int b = blockIdx.x;
  const int lane = (int)threadIdx.x;
  const int g = lane >> 3;        // group index
  const int l = lane & 7;         // in-group index
  const bool lhi = (l >= 6);
  const bool ghi = (g >= 6);
  const bool sel4 = (lane & 4) != 0;
  const int gg = (g < 6) ? g : 5;
  const int jj = lhi ? 5 : l;
  // A-step (odd t): roles i=g, j=l; B-step (even t): roles i=l, j=g
  const int offTA = gg * 6 + jj;   // trans[t][i=g][j=l]
  const int offTB = jj * 6 + gg;   // trans[t][i=l][j=g]
  const int offFA = gg;            // feat[t][i=g]
  const int offFB = jj;            // feat[t][i=l]
  const float ninf = __int_as_float(0xff800000u);

  const float* trb = trans + (size_t)b * NT * 36;
  const float* ftb = feats + (size_t)b * NT * 6;

  // layout0: lane (g,l) holds delta[l]
  float delta = (l == 4) ? 0.0f : ((l < 6) ? -10000.0f : ninf);
  u32 mlo = 0, mhi = 0;

  auto stage = [&](int c) {
    const int buf = c & 1;
    const float* gt = trb + (size_t)c * CH * 36;
    float* lt = s_tr + buf * (CH * 36);
#pragma unroll
    for (int i = 0; i < 18; ++i) gll16(gt + i * 256 + lane * 4, lt + i * 256);
    const float* gf = ftb + (size_t)c * CH * 6;
    float* lf = s_ft + buf * (CH * 6);
#pragma unroll
    for (int i = 0; i < 3; ++i) gll16(gf + i * 256 + lane * 4, lf + i * 256);
  };

  // consumes layout0, produces layout1 (lane (g,l) -> delta_new[g])
  auto stepA = [&](float tr, float ft, int slot) {
    float s = tr + delta;                              // tr pre-masked (lhi)
    float m = fmaxf(s, dppf<0xB1>(s));                 // xor1
    m = fmaxf(m, dppf<0x4E>(m));                       // xor2
    float r4 = dppf<0x124>(m);                         // from lane i-4
    float r12 = dppf<0x12C>(m);                        // from lane i+4
    m = fmaxf(m, sel4 ? r4 : r12);                     // xor4
    u64 bal = __ballot(s == m);                        // bits at 8i+j
    bool cap = (lane == slot);
    mlo = cap ? (u32)bal : mlo;
    mhi = cap ? (u32)(bal >> 32) : mhi;
    delta = m + ft;
  };

  // consumes layout1, produces layout0 (lane (g,l) -> delta_new[l])
  auto stepB = [&](float tr, float ft, int slot) {
    float s = tr + delta;                              // tr pre-masked (ghi)
    float m = fmaxf(s, dppf<0x128>(s));                // xor8 (row_ror:8)
    m = pl16max(m);                                    // xor16
    m = pl32max(m);                                    // xor32
    u64 bal = __ballot(s == m);                        // bits at 8j+i
    bool cap = (lane == slot);
    mlo = cap ? (u32)bal : mlo;
    mhi = cap ? (u32)(bal >> 32) : mhi;
    delta = m + ft;
  };

  auto flush = [&](int base) {  // lane holds ballot of step base+lane
    const u32 ub = (u32)(base >> 6) & 63;
    // A-unpack (odd step => odd lane): psi_i = ctz of (bal >> 8i) & 63
    u32 pA = (u32)__builtin_ctz((mlo & 63u) | 64u);
    pA |= (u32)__builtin_ctz(((mlo >> 8) & 63u) | 64u) << 3;
    pA |= (u32)__builtin_ctz(((mlo >> 16) & 63u) | 64u) << 6;
    pA |= (u32)__builtin_ctz(((mlo >> 24) & 63u) | 64u) << 9;
    pA |= (u32)__builtin_ctz((mhi & 63u) | 64u) << 12;
    pA |= (u32)__builtin_ctz(((mhi >> 8) & 63u) | 64u) << 15;
    // B-unpack (even step => even lane): bits for state i at 8j+i
    u64 bal = ((u64)mhi << 32) | (u64)mlo;
    u32 pB = 0;
#pragma unroll
    for (int i = 0; i < 6; ++i) {
      u64 mm = (bal >> i) & 0x0000010101010101ULL;
      u32 j = (u32)(__builtin_ctzll(mm | (1ULL << 48)) >> 3);
      pB |= j << (3 * i);
    }
    u32 p = (lane & 1) ? pA : pB;
    s_psi[base + (((u32)lane) ^ ub)] = p;   // bank-swizzled slot
  };

  stage(0);
  asm volatile("s_waitcnt vmcnt(0)" ::: "memory");
  stage(1);

  // ---- chunk 0 (t = 1..127; t=0 skipped). t odd -> stepA, t even -> stepB.
  {
    const float* trp = s_tr;
    const float* ftp = s_ft;
#pragma unroll
    for (int k = 1; k < 8; ++k) {
      if (k & 1) {
        float tv = lhi ? ninf : trp[k * 36 + offTA];
        stepA(tv, ftp[k * 6 + offFA], k);
      } else {
        float tv = ghi ? ninf : trp[k * 36 + offTB];
        stepB(tv, ftp[k * 6 + offFB], k);
      }
    }
    for (int k8 = 8; k8 < CH; k8 += 8) {
      float trv[8], ftv[8];
#pragma unroll
      for (int q = 0; q < 8; ++q) {
        if (q & 1) {  // odd t
          trv[q] = lhi ? ninf : trp[(k8 + q) * 36 + offTA];
          ftv[q] = ftp[(k8 + q) * 6 + offFA];
        } else {      // even t
          trv[q] = ghi ? ninf : trp[(k8 + q) * 36 + offTB];
          ftv[q] = ftp[(k8 + q) * 6 + offFB];
        }
      }
#pragma unroll
      for (int q = 0; q < 8; ++q) {
        if (q & 1) stepA(trv[q], ftv[q], (k8 + q) & 63);
        else       stepB(trv[q], ftv[q], (k8 + q) & 63);
      }
      if ((k8 & 63) == 56) flush(k8 - 56);
    }
  }

  // ---- chunks 1..31 (tbase even => t parity == q parity)
  for (int c = 1; c < NCHUNK; ++c) {
    asm volatile("s_waitcnt vmcnt(0)" ::: "memory");   // chunk c resident
    if (c + 1 < NCHUNK) stage(c + 1);
    const int buf = c & 1;
    const float* trp = s_tr + buf * (CH * 36);
    const float* ftp = s_ft + buf * (CH * 6);
    const int tbase = c * CH;
    for (int k8 = 0; k8 < CH; k8 += 8) {
      float trv[8], ftv[8];
#pragma unroll
      for (int q = 0; q < 8; ++q) {
        if (q & 1) {
          trv[q] = lhi ? ninf : trp[(k8 + q) * 36 + offTA];
          ftv[q] = ftp[(k8 + q) * 6 + offFA];
        } else {
          trv[q] = ghi ? ninf : trp[(k8 + q) * 36 + offTB];
          ftv[q] = ftp[(k8 + q) * 6 + offFB];
        }
      }
#pragma unroll
      for (int q = 0; q < 8; ++q) {
        if (q & 1) stepA(trv[q], ftv[q], (k8 + q) & 63);
        else       stepB(trv[q], ftv[q], (k8 + q) & 63);
      }
      if ((k8 & 63) == 56) flush(tbase + k8 - 56);
    }
  }

  // ---- score + last_tag. Final step t=4095 is stepA -> layout1:
  // lane (g,l) holds delta_final[g]; groups 6,7 duplicate state 5 exactly.
  float sm = delta;
  sm = fmaxf(sm, dppf<0xB1>(sm));
  sm = fmaxf(sm, dppf<0x4E>(sm));
  {
    float q4 = dppf<0x124>(sm), q12 = dppf<0x12C>(sm);
    sm = fmaxf(sm, sel4 ? q4 : q12);
  }
  sm = fmaxf(sm, dppf<0x128>(sm));
  sm = pl16max(sm);
  sm = pl32max(sm);
  u64 bs = __ballot(delta == sm);
  int last_tag = (int)((__builtin_ctzll(bs) >> 3) & 7);  // smallest g wins ties

  __syncthreads();  // all psi visible

  // ---- per-segment backpointer-map composition (exact integer scan)
  const int u = lane;
  u32 Gm = 0u | (1u << 3) | (2u << 6) | (3u << 9) | (4u << 12) | (5u << 15);
  for (int k = 0; k < 64; ++k) {
    u32 p = s_psi[u * 64 + (k ^ u)];
    u32 ng = 0;
#pragma unroll
    for (int x = 0; x < 6; ++x) {
      u32 j = (p >> (3 * x)) & 7;
      u32 v = (Gm >> (3 * ((j < 6) ? j : 0))) & 7;  // clamp garbage fields
      ng |= v << (3 * x);
    }
    Gm = ng;
  }

  // ---- boundary-tag chain via readlane (uniform, register-only)
  int bcur = last_tag;
  int my_b = last_tag;  // lane 63
  for (int v = 63; v >= 1; --v) {
    u32 Gv = (u32)__builtin_amdgcn_readlane((int)Gm, v);
    bcur = (int)((Gv >> (3 * bcur)) & 7);
    my_b = (u == v - 1) ? bcur : my_b;
  }

  // ---- per-segment walk, emit path bytes
  {
    int tag = my_b;
    unsigned char* pb = (unsigned char*)s_path;
    pb[u * 64 + 63] = (unsigned char)tag;
    for (int k = 63; k >= 1; --k) {
      u32 p = s_psi[u * 64 + (k ^ u)];
      tag = (int)((p >> (3 * tag)) & 7);
      pb[u * 64 + k - 1] = (unsigned char)tag;
    }
  }
  if (lane == 0) out[b] = sm;
  __syncthreads();

  // ---- coalesced float path store
  float* outp = out + NB + (size_t)b * NT;
#pragma unroll
  for (int i = 0; i < (NT / 4) / 64; ++i) {
    u32 w = s_path[lane + i * 64];
    float4 f;
    f.x = (float)(w & 255u);
    f.y = (float)((w >> 8) & 255u);
    f.z = (float)((w >> 16) & 255u);
    f.w = (float)((w >> 24) & 255u);
    ((float4*)outp)[lane + i * 64] = f;
  }
}

extern "C" void kernel_launch(void* const* d_in, const int* in_sizes, int n_in,
                              void* d_out, int out_size, void* d_ws, size_t ws_size,
                              hipStream_t stream) {
  (void)in_sizes; (void)n_in; (void)out_size; (void)d_ws; (void)ws_size;
  const float* feats = (const float*)d_in[0];
  const float* trans = (const float*)d_in[1];
  float* out = (float*)d_out;
  hipLaunchKernelGGL(viterbi_k, dim3(NB), dim3(64), 0, stream, feats, trans, out);
}

// Round 5
// 251.291 us; speedup vs baseline: 1.4171x; 1.2413x over previous
//
#include <hip/hip_runtime.h>

#define NB 256
#define NT 4096
#define CH 128
#define NCHUNK (NT / CH)

typedef unsigned int u32;
typedef unsigned long long u64;
typedef int v2i __attribute__((ext_vector_type(2)));

typedef __attribute__((address_space(1))) const u32 gas_u32;
typedef __attribute__((address_space(3))) u32 las_u32;

__device__ __forceinline__ void gll16(const void* g, void* l) {
  __builtin_amdgcn_global_load_lds((gas_u32*)g, (las_u32*)l, 16, 0, 0);
}

template <int CTRL>
__device__ __forceinline__ float dppf(float x) {
  return __int_as_float(__builtin_amdgcn_update_dpp(
      0, __float_as_int(x), CTRL, 0xF, 0xF, true));
}

// max with lane^16 partner (cross-row), VALU-speed on gfx950
__device__ __forceinline__ float pl16max(float x) {
#if __has_builtin(__builtin_amdgcn_permlane16_swap)
  v2i r = __builtin_amdgcn_permlane16_swap(__float_as_int(x), __float_as_int(x),
                                           false, false);
  return fmaxf(__int_as_float(r[0]), __int_as_float(r[1]));
#else
  return fmaxf(x, __shfl_xor(x, 16, 64));
#endif
}

// max with lane^32 partner
__device__ __forceinline__ float pl32max(float x) {
#if __has_builtin(__builtin_amdgcn_permlane32_swap)
  v2i r = __builtin_amdgcn_permlane32_swap(__float_as_int(x), __float_as_int(x),
                                           false, false);
  return fmaxf(__int_as_float(r[0]), __int_as_float(r[1]));
#else
  return fmaxf(x, __shfl_xor(x, 32, 64));
#endif
}

__global__ void __launch_bounds__(64, 1)
viterbi_k(const float* __restrict__ feats, const float* __restrict__ trans,
          float* __restrict__ out) {
  // LDS: 36864 + 6144 + 16384 + 4096 = 63488 B (< 64KB)
  __shared__ __align__(16) float s_tr[2 * CH * 36];
  __shared__ __align__(16) float s_ft[2 * CH * 6];
  __shared__ u32 s_psi[NT];
  __shared__ u32 s_path[NT / 4];

  const int b = blockIdx.x;
  const int lane = (int)threadIdx.x;
  const int g = lane >> 3;        // group index
  const int l = lane & 7;         // in-group index
  const bool lhi = (l >= 6);
  const bool ghi = (g >= 6);
  const bool sel4 = (lane & 4) != 0;
  const int gg = (g < 6) ? g : 5;
  const int jj = lhi ? 5 : l;
  // A-step (odd t): roles i=g, j=l; B-step (even t): roles i=l, j=g
  const int offTA = gg * 6 + jj;   // trans[t][i=g][j=l]
  const int offTB = jj * 6 + gg;   // trans[t][i=l][j=g]
  const int offFA = gg;            // feat[t][i=g]
  const int offFB = jj;            // feat[t][i=l]
  const float ninf = __int_as_float(0xff800000u);

  const float* trb = trans + (size_t)b * NT * 36;
  const float* ftb = feats + (size_t)b * NT * 6;

  // layout0: lane (g,l) holds delta[l]
  float delta = (l == 4) ? 0.0f : ((l < 6) ? -10000.0f : ninf);
  u32 mlo = 0, mhi = 0;

  auto stage = [&](int c) {
    const int buf = c & 1;
    const float* gt = trb + (size_t)c * CH * 36;
    float* lt = s_tr + buf * (CH * 36);
#pragma unroll
    for (int i = 0; i < 18; ++i) gll16(gt + i * 256 + lane * 4, lt + i * 256);
    const float* gf = ftb + (size_t)c * CH * 6;
    float* lf = s_ft + buf * (CH * 6);
#pragma unroll
    for (int i = 0; i < 3; ++i) gll16(gf + i * 256 + lane * 4, lf + i * 256);
  };

  // consumes layout0, produces layout1 (lane (g,l) -> delta_new[g])
  auto stepA = [&](float tr, float ft, int slot) {
    float s = tr + delta;                              // tr pre-masked (lhi)
    float m = fmaxf(s, dppf<0xB1>(s));                 // xor1
    m = fmaxf(m, dppf<0x4E>(m));                       // xor2
    float r4 = dppf<0x124>(m);                         // from lane i-4
    float r12 = dppf<0x12C>(m);                        // from lane i+4
    m = fmaxf(m, sel4 ? r4 : r12);                     // xor4
    u64 bal = __ballot(s == m);                        // bits at 8i+j
    bool cap = (lane == slot);
    mlo = cap ? (u32)bal : mlo;
    mhi = cap ? (u32)(bal >> 32) : mhi;
    delta = m + ft;
  };

  // consumes layout1, produces layout0 (lane (g,l) -> delta_new[l])
  auto stepB = [&](float tr, float ft, int slot) {
    float s = tr + delta;                              // tr pre-masked (ghi)
    float m = fmaxf(s, dppf<0x128>(s));                // xor8 (row_ror:8)
    m = pl16max(m);                                    // xor16
    m = pl32max(m);                                    // xor32
    u64 bal = __ballot(s == m);                        // bits at 8j+i
    bool cap = (lane == slot);
    mlo = cap ? (u32)bal : mlo;
    mhi = cap ? (u32)(bal >> 32) : mhi;
    delta = m + ft;
  };

  auto flush = [&](int base) {  // lane holds ballot of step base+lane
    const u32 ub = (u32)(base >> 6) & 63;
    // A-unpack (odd step => odd lane): psi_i = ctz of (bal >> 8i) & 63
    u32 pA = (u32)__builtin_ctz((mlo & 63u) | 64u);
    pA |= (u32)__builtin_ctz(((mlo >> 8) & 63u) | 64u) << 3;
    pA |= (u32)__builtin_ctz(((mlo >> 16) & 63u) | 64u) << 6;
    pA |= (u32)__builtin_ctz(((mlo >> 24) & 63u) | 64u) << 9;
    pA |= (u32)__builtin_ctz((mhi & 63u) | 64u) << 12;
    pA |= (u32)__builtin_ctz(((mhi >> 8) & 63u) | 64u) << 15;
    // B-unpack (even step => even lane): bits for state i at 8j+i
    u64 bal = ((u64)mhi << 32) | (u64)mlo;
    u32 pB = 0;
#pragma unroll
    for (int i = 0; i < 6; ++i) {
      u64 mm = (bal >> i) & 0x0000010101010101ULL;
      u32 j = (u32)(__builtin_ctzll(mm | (1ULL << 48)) >> 3);
      pB |= j << (3 * i);
    }
    u32 p = (lane & 1) ? pA : pB;
    s_psi[base + (((u32)lane) ^ ub)] = p;   // bank-swizzled slot
  };

// group load: 8 steps' (tr, ft) into register arrays (static indices only)
#define LOAD8(trv, ftv, g8base)                                               \
  {                                                                           \
    _Pragma("unroll") for (int q = 0; q < 8; ++q) {                           \
      trv[q] = trp[((g8base) + q) * 36 + ((q & 1) ? offTA : offTB)];          \
      ftv[q] = ftp[((g8base) + q) * 6 + ((q & 1) ? offFA : offFB)];           \
    }                                                                         \
  }

#define STEPS8(trv, ftv, base)                                                \
  {                                                                           \
    _Pragma("unroll") for (int q = 0; q < 8; ++q) {                           \
      if (q & 1) stepA(lhi ? ninf : trv[q], ftv[q], ((base) + q) & 63);       \
      else       stepB(ghi ? ninf : trv[q], ftv[q], ((base) + q) & 63);       \
    }                                                                         \
  }

  stage(0);
  asm volatile("s_waitcnt vmcnt(0)" ::: "memory");
  stage(1);

  // ---- chunk 0 (t = 1..127; t=0 skipped). t odd -> stepA, t even -> stepB.
  {
    const float* trp = s_tr;
    const float* ftp = s_ft;
    float trA[8], ftA[8], trB[8], ftB[8];
    LOAD8(trA, ftA, 0);
    LOAD8(trB, ftB, 8);
    // steps 1..7 (skip t=0)
#pragma unroll
    for (int q = 1; q < 8; ++q) {
      if (q & 1) stepA(lhi ? ninf : trA[q], ftA[q], q);
      else       stepB(ghi ? ninf : trA[q], ftA[q], q);
    }
    LOAD8(trA, ftA, 16);
    STEPS8(trB, ftB, 8);
#pragma unroll 1
    for (int g2 = 2; g2 < 16; g2 += 2) {
      LOAD8(trB, ftB, (g2 + 1) * 8);
      STEPS8(trA, ftA, g2 * 8);
      LOAD8(trA, ftA, (g2 + 2) * 8);   // g2==14 -> in-LDS garbage, never consumed
      STEPS8(trB, ftB, (g2 + 1) * 8);
      if ((g2 & 7) == 6) flush((g2 & 8) * 8);
    }
  }

  // ---- chunks 1..31 (tbase even => t parity == q parity)
#pragma unroll 1
  for (int c = 1; c < NCHUNK; ++c) {
    asm volatile("s_waitcnt vmcnt(0)" ::: "memory");   // chunk c resident
    if (c + 1 < NCHUNK) stage(c + 1);
    const int buf = c & 1;
    const float* trp = s_tr + buf * (CH * 36);
    const float* ftp = s_ft + buf * (CH * 6);
    const int tbase = c * CH;
    float trA[8], ftA[8], trB[8], ftB[8];
    LOAD8(trA, ftA, 0);
#pragma unroll 1
    for (int g2 = 0; g2 < 16; g2 += 2) {
      LOAD8(trB, ftB, (g2 + 1) * 8);
      STEPS8(trA, ftA, tbase + g2 * 8);
      LOAD8(trA, ftA, (g2 + 2) * 8);   // g2==14 -> in-LDS garbage, never consumed
      STEPS8(trB, ftB, tbase + (g2 + 1) * 8);
      if ((g2 & 7) == 6) flush(tbase + (g2 & 8) * 8);
    }
  }

  // ---- score + last_tag. Final step t=4095 is stepA -> layout1:
  // lane (g,l) holds delta_final[g]; groups 6,7 duplicate state 5 exactly.
  float sm = delta;
  sm = fmaxf(sm, dppf<0xB1>(sm));
  sm = fmaxf(sm, dppf<0x4E>(sm));
  {
    float q4 = dppf<0x124>(sm), q12 = dppf<0x12C>(sm);
    sm = fmaxf(sm, sel4 ? q4 : q12);
  }
  sm = fmaxf(sm, dppf<0x128>(sm));
  sm = pl16max(sm);
  sm = pl32max(sm);
  u64 bs = __ballot(delta == sm);
  int last_tag = (int)((__builtin_ctzll(bs) >> 3) & 7);  // smallest g wins ties

  __syncthreads();  // all psi visible

  // ---- per-segment backpointer-map composition (exact integer scan)
  const int u = lane;
  u32 Gm = 0u | (1u << 3) | (2u << 6) | (3u << 9) | (4u << 12) | (5u << 15);
#pragma unroll 1
  for (int k = 0; k < 64; ++k) {
    u32 p = s_psi[u * 64 + (k ^ u)];
    u32 ng = 0;
#pragma unroll
    for (int x = 0; x < 6; ++x) {
      u32 j = (p >> (3 * x)) & 7;
      u32 v = (Gm >> (3 * ((j < 6) ? j : 0))) & 7;  // clamp garbage fields
      ng |= v << (3 * x);
    }
    Gm = ng;
  }

  // ---- boundary-tag chain via readlane (uniform, register-only)
  int bcur = last_tag;
  int my_b = last_tag;  // lane 63
#pragma unroll 1
  for (int v = 63; v >= 1; --v) {
    u32 Gv = (u32)__builtin_amdgcn_readlane((int)Gm, v);
    bcur = (int)((Gv >> (3 * bcur)) & 7);
    my_b = (u == v - 1) ? bcur : my_b;
  }

  // ---- per-segment walk, emit path bytes
  {
    int tag = my_b;
    unsigned char* pb = (unsigned char*)s_path;
    pb[u * 64 + 63] = (unsigned char)tag;
#pragma unroll 1
    for (int k = 63; k >= 1; --k) {
      u32 p = s_psi[u * 64 + (k ^ u)];
      tag = (int)((p >> (3 * tag)) & 7);
      pb[u * 64 + k - 1] = (unsigned char)tag;
    }
  }
  if (lane == 0) out[b] = sm;
  __syncthreads();

  // ---- coalesced float path store
  float* outp = out + NB + (size_t)b * NT;
#pragma unroll
  for (int i = 0; i < (NT / 4) / 64; ++i) {
    u32 w = s_path[lane + i * 64];
    float4 f;
    f.x = (float)(w & 255u);
    f.y = (float)((w >> 8) & 255u);
    f.z = (float)((w >> 16) & 255u);
    f.w = (float)((w >> 24) & 255u);
    ((float4*)outp)[lane + i * 64] = f;
  }
}

extern "C" void kernel_launch(void* const* d_in, const int* in_sizes, int n_in,
                              void* d_out, int out_size, void* d_ws, size_t ws_size,
                              hipStream_t stream) {
  (void)in_sizes; (void)n_in; (void)out_size; (void)d_ws; (void)ws_size;
  const float* feats = (const float*)d_in[0];
  const float* trans = (const float*)d_in[1];
  float* out = (float*)d_out;
  hipLaunchKernelGGL(viterbi_k, dim3(NB), dim3(64), 0, stream, feats, trans, out);
}